// Round 1
// baseline (74.004 us; speedup 1.0000x reference)
//
#include <hip/hip_runtime.h>
#include <hip/hip_fp16.h>

typedef _Float16 half8 __attribute__((ext_vector_type(8)));
typedef float f32x4 __attribute__((ext_vector_type(4)));

#define N_INNER 511
#define NPAD 512
#define FEAT 1024
#define BATCH 16384
#define NCLS 100
#define NCLSPAD 112

// ---------------- prep: W -> f16 [512][1024] (row 511 zero); leaf_logits -> LT f16 [112][512] ----------------
__global__ void k_prep(const float* __restrict__ W, const float* __restrict__ L,
                       _Float16* __restrict__ Wh, _Float16* __restrict__ LT) {
  int i = blockIdx.x * 256 + threadIdx.x;
  if (i < NPAD * FEAT) {
    int n = i >> 10;
    Wh[i] = (n < N_INNER) ? (_Float16)W[i] : (_Float16)0.f;
  }
  if (i < NCLSPAD * NPAD) {
    int n = i >> 9, k = i & 511;
    LT[i] = (n < NCLS) ? (_Float16)L[k * NCLS + n] : (_Float16)0.f;
  }
}

// ---------------- GEMM1: gates = sigmoid(x @ Wh^T + b), f16 out [16384][512] ----------------
// 128x128 tile, BK=32, 256 threads (4 waves, 2x2), reg-staged (f32->f16 convert), dbuf LDS pad 40
#define LDK 40

__global__ __launch_bounds__(256, 2) void k_gemm1(
    const float* __restrict__ x, const _Float16* __restrict__ Wh,
    const float* __restrict__ bias, _Float16* __restrict__ gates) {
  __shared__ _Float16 lA[2][128 * LDK];
  __shared__ _Float16 lB[2][128 * LDK];

  const int t = threadIdx.x;
  const int lane = t & 63;
  const int w = t >> 6;
  const int wm = w >> 1, wn = w & 1;
  const int bx = blockIdx.x;
  const int bn = bx & 3;
  const int bm = bx >> 2;

  const float* xb = x + (size_t)bm * 128 * FEAT;
  const _Float16* wb = Wh + (size_t)bn * 128 * FEAT;

  // staging tasks: 512 segments of 8 elems (row, kseg); this thread does s and s+256
  const int r0 = t >> 2, ks0 = t & 3;
  const int r1 = (t + 256) >> 2, ks1 = (t + 256) & 3;

  f32x4 acc[4][4] = {};

  float4 xv0a, xv0b, xv1a, xv1b;
  uint4 wv0, wv1;

  auto load_stage = [&](int k0) {
    xv0a = *(const float4*)(xb + (size_t)r0 * FEAT + k0 + ks0 * 8);
    xv0b = *(const float4*)(xb + (size_t)r0 * FEAT + k0 + ks0 * 8 + 4);
    xv1a = *(const float4*)(xb + (size_t)r1 * FEAT + k0 + ks1 * 8);
    xv1b = *(const float4*)(xb + (size_t)r1 * FEAT + k0 + ks1 * 8 + 4);
    wv0 = *(const uint4*)(wb + (size_t)r0 * FEAT + k0 + ks0 * 8);
    wv1 = *(const uint4*)(wb + (size_t)r1 * FEAT + k0 + ks1 * 8);
  };

  auto write_stage = [&](int B) {
    half8 h0, h1;
    h0[0] = (_Float16)xv0a.x; h0[1] = (_Float16)xv0a.y; h0[2] = (_Float16)xv0a.z; h0[3] = (_Float16)xv0a.w;
    h0[4] = (_Float16)xv0b.x; h0[5] = (_Float16)xv0b.y; h0[6] = (_Float16)xv0b.z; h0[7] = (_Float16)xv0b.w;
    h1[0] = (_Float16)xv1a.x; h1[1] = (_Float16)xv1a.y; h1[2] = (_Float16)xv1a.z; h1[3] = (_Float16)xv1a.w;
    h1[4] = (_Float16)xv1b.x; h1[5] = (_Float16)xv1b.y; h1[6] = (_Float16)xv1b.z; h1[7] = (_Float16)xv1b.w;
    *(half8*)&lA[B][r0 * LDK + ks0 * 8] = h0;
    *(half8*)&lA[B][r1 * LDK + ks1 * 8] = h1;
    *(uint4*)&lB[B][r0 * LDK + ks0 * 8] = wv0;
    *(uint4*)&lB[B][r1 * LDK + ks1 * 8] = wv1;
  };

  load_stage(0);
  write_stage(0);
  __syncthreads();

  for (int kk = 0; kk < 32; ++kk) {
    const int buf = kk & 1;
    if (kk < 31) load_stage((kk + 1) * 32);

    half8 af[4], bf[4];
#pragma unroll
    for (int i = 0; i < 4; ++i) {
      af[i] = *(const half8*)&lA[buf][(wm * 64 + i * 16 + (lane & 15)) * LDK + (lane >> 4) * 8];
      bf[i] = *(const half8*)&lB[buf][(wn * 64 + i * 16 + (lane & 15)) * LDK + (lane >> 4) * 8];
    }
#pragma unroll
    for (int i = 0; i < 4; ++i)
#pragma unroll
      for (int j = 0; j < 4; ++j)
        acc[i][j] = __builtin_amdgcn_mfma_f32_16x16x32_f16(af[i], bf[j], acc[i][j], 0, 0, 0);

    if (kk < 31) write_stage(buf ^ 1);
    __syncthreads();
  }

  // epilogue: bias + sigmoid, store f16
#pragma unroll
  for (int j = 0; j < 4; ++j) {
    const int col = bn * 128 + wn * 64 + j * 16 + (lane & 15);
    const float bb = (col < N_INNER) ? bias[col] : 0.f;
#pragma unroll
    for (int i = 0; i < 4; ++i) {
      const int rowb = bm * 128 + wm * 64 + i * 16 + ((lane >> 4) << 2);
#pragma unroll
      for (int r = 0; r < 4; ++r) {
        float v = acc[i][j][r] + bb;
        v = 1.f / (1.f + __expf(-v));
        gates[(size_t)(rowb + r) * NPAD + col] = (_Float16)v;
      }
    }
  }
}

// ---------------- K2: tree expansion + GEMM2 (prob @ leaf_logits) ----------------
// 256 blocks x 64 rows, 512 threads. Phase1: 8 threads/row expand 64 leaves each (regs, f32).
// Phase2: MFMA, A = leafp (LDS, padded stride 520), B = LT rows from global (L2-resident).
#define LPS 520  // leafp LDS stride (512 + 8 pad -> 2-way bank aliasing, free)

__global__ __launch_bounds__(512, 2) void k_tree(
    const _Float16* __restrict__ gates, const _Float16* __restrict__ LT,
    float* __restrict__ out) {
  __shared__ _Float16 lp[64 * LPS];

  const int t = threadIdx.x;
  const int rowl = t >> 3, sub = t & 7;
  const size_t grow = (size_t)blockIdx.x * 64 + rowl;
  const _Float16* g = gates + grow * NPAD;

  // top 3 levels: leaf bits b8 b7 b6 = sub
  const float f0 = (float)g[0];
  const float f1 = (float)g[1 + (sub >> 2)];
  const float f2 = (float)g[3 + (sub >> 1)];
  float p = ((sub & 4) ? f0 : 1.f - f0) * ((sub & 2) ? f1 : 1.f - f1) * ((sub & 1) ? f2 : 1.f - f2);

  float arr[64];
  arr[0] = p;
#pragma unroll
  for (int lvl = 3; lvl <= 8; ++lvl) {
    const int cnt = 1 << (lvl - 3);
    const int off = (1 << lvl) - 1;
    const int nb = sub << (lvl - 3);
#pragma unroll
    for (int i = cnt - 1; i >= 0; --i) {
      const float gg = (float)g[off + nb + i];
      const float pp = arr[i];
      arr[2 * i + 1] = pp * gg;
      arr[2 * i] = pp - pp * gg;
    }
  }

  const int lb = sub * 64;
#pragma unroll
  for (int i = 0; i < 64; i += 8) {
    half8 h;
#pragma unroll
    for (int j = 0; j < 8; ++j) h[j] = (_Float16)arr[i + j];
    *(half8*)&lp[rowl * LPS + lb + i] = h;
  }
  __syncthreads();

  // phase 2: 8 waves; wave = (mf 0..3, nh 0..1). nh0: n-frags 0-3, nh1: n-frags 4-6.
  const int lane = t & 63, w = t >> 6;
  const int mf = w & 3, nh = w >> 2;

  f32x4 acc[4] = {};
#pragma unroll
  for (int k0 = 0; k0 < 512; k0 += 32) {
    const half8 a = *(const half8*)&lp[(mf * 16 + (lane & 15)) * LPS + k0 + (lane >> 4) * 8];
#pragma unroll
    for (int j = 0; j < 4; ++j) {
      if (nh == 0 || j < 3) {
        const int n = nh * 64 + j * 16 + (lane & 15);
        const half8 b8 = *(const half8*)&LT[(size_t)n * NPAD + k0 + (lane >> 4) * 8];
        acc[j] = __builtin_amdgcn_mfma_f32_16x16x32_f16(a, b8, acc[j], 0, 0, 0);
      }
    }
  }

#pragma unroll
  for (int j = 0; j < 4; ++j) {
    if (nh && j == 3) continue;
    const int col = nh * 64 + j * 16 + (lane & 15);
    if (col < NCLS) {
#pragma unroll
      for (int r = 0; r < 4; ++r) {
        const int row = blockIdx.x * 64 + mf * 16 + ((lane >> 4) << 2) + r;
        out[(size_t)row * NCLS + col] = acc[j][r];
      }
    }
  }
}

extern "C" void kernel_launch(void* const* d_in, const int* in_sizes, int n_in,
                              void* d_out, int out_size, void* d_ws, size_t ws_size,
                              hipStream_t stream) {
  const float* x = (const float*)d_in[0];
  const float* W = (const float*)d_in[1];
  const float* b = (const float*)d_in[2];
  const float* L = (const float*)d_in[3];
  float* out = (float*)d_out;

  char* ws = (char*)d_ws;
  _Float16* Wh = (_Float16*)ws;                                  // 512*1024*2 = 1 MB
  _Float16* LT = (_Float16*)(ws + (1u << 20));                   // 112*512*2 = 112 KB
  _Float16* gates = (_Float16*)(ws + (1u << 20) + 114688u);      // 16384*512*2 = 16 MB

  k_prep<<<2048, 256, 0, stream>>>(W, L, Wh, LT);
  k_gemm1<<<512, 256, 0, stream>>>(x, Wh, b, gates);
  k_tree<<<256, 512, 0, stream>>>(gates, LT, out);
}

// Round 2
// 53.758 us; speedup vs baseline: 1.3766x; 1.3766x over previous
//
#include <hip/hip_runtime.h>
#include <hip/hip_fp16.h>

typedef _Float16 half8 __attribute__((ext_vector_type(8)));
typedef _Float16 half4v __attribute__((ext_vector_type(4)));
typedef _Float16 half2v __attribute__((ext_vector_type(2)));
typedef float f32x4 __attribute__((ext_vector_type(4)));

#define N_INNER 511
#define NPAD 512
#define FEAT 1024
#define BATCH 16384
#define NCLS 100
#define NCLSPAD 112

// ---------------- prep: W -> f16 [512][1024] (row 511 zero); leaf_logits -> LT f16 [112][512] ----------------
__global__ void k_prep(const float* __restrict__ W, const float* __restrict__ L,
                       _Float16* __restrict__ Wh, _Float16* __restrict__ LT) {
  int i = blockIdx.x * 256 + threadIdx.x;
  if (i < NPAD * FEAT) {
    int n = i >> 10;
    Wh[i] = (n < N_INNER) ? (_Float16)W[i] : (_Float16)0.f;
  }
  if (i < NCLSPAD * NPAD) {
    int n = i >> 9, k = i & 511;
    LT[i] = (n < NCLS) ? (_Float16)L[k * NCLS + n] : (_Float16)0.f;
  }
}

// ---------------- GEMM1: gates = sigmoid(x @ Wh^T + b), heap-layout f16 out [16384][512] ----------------
// 128x128 tile, BK=32, 512 threads (8 waves 2x4), reg-staged dbuf, LDK=40 pad.
// Gate for inner node col (breadth-first) stored at heap position col+1 (level lvl at [2^lvl, 2^(lvl+1))).
#define LDK 40

__global__ __launch_bounds__(512, 4) void k_gemm1(
    const float* __restrict__ x, const _Float16* __restrict__ Wh,
    const float* __restrict__ bias, _Float16* __restrict__ gates) {
  __shared__ _Float16 lA[2][128 * LDK];
  __shared__ _Float16 lB[2][128 * LDK];

  const int t = threadIdx.x;
  const int lane = t & 63;
  const int w = t >> 6;
  const int wm = w >> 2, wn = w & 3;   // 2 x 4 waves

  // XCD swizzle: 4 bn-siblings of each bm on the same XCD
  const int bid = blockIdx.x;
  const int xcd = bid & 7, j = bid >> 3;
  const int bm = (j >> 2) * 8 + xcd;   // 0..127
  const int bn = j & 3;                // 0..3

  const float* xb = x + (size_t)bm * 128 * FEAT;
  const _Float16* wb = Wh + (size_t)bn * 128 * FEAT;

  // staging: 512 tasks (row 0..127, seg 0..3 of 8 elems), 1 per thread
  const int sr = t >> 2, ss = t & 3;
  const float* pa = xb + (size_t)sr * FEAT + ss * 8;
  const _Float16* pb = wb + (size_t)sr * FEAT + ss * 8;
  const int lds_off = sr * LDK + ss * 8;

  f32x4 acc[4][2] = {};

  float4 xa, xbv;
  uint4 wv;

  auto load_stage = [&](int k0) {
    xa  = *(const float4*)(pa + k0);
    xbv = *(const float4*)(pa + k0 + 4);
    wv  = *(const uint4*)(pb + k0);
  };

  auto write_stage = [&](int B) {
    half8 h;
    h[0] = (_Float16)xa.x;  h[1] = (_Float16)xa.y;  h[2] = (_Float16)xa.z;  h[3] = (_Float16)xa.w;
    h[4] = (_Float16)xbv.x; h[5] = (_Float16)xbv.y; h[6] = (_Float16)xbv.z; h[7] = (_Float16)xbv.w;
    *(half8*)&lA[B][lds_off] = h;
    *(uint4*)&lB[B][lds_off] = wv;
  };

  load_stage(0);
  write_stage(0);
  __syncthreads();

  for (int kk = 0; kk < 32; ++kk) {
    const int buf = kk & 1;
    if (kk < 31) load_stage((kk + 1) * 32);

    half8 af[4], bf[2];
#pragma unroll
    for (int i = 0; i < 4; ++i)
      af[i] = *(const half8*)&lA[buf][(wm * 64 + i * 16 + (lane & 15)) * LDK + (lane >> 4) * 8];
#pragma unroll
    for (int jn = 0; jn < 2; ++jn)
      bf[jn] = *(const half8*)&lB[buf][(wn * 32 + jn * 16 + (lane & 15)) * LDK + (lane >> 4) * 8];

#pragma unroll
    for (int i = 0; i < 4; ++i)
#pragma unroll
      for (int jn = 0; jn < 2; ++jn)
        acc[i][jn] = __builtin_amdgcn_mfma_f32_16x16x32_f16(af[i], bf[jn], acc[i][jn], 0, 0, 0);

    if (kk < 31) write_stage(buf ^ 1);
    __syncthreads();
  }

  // epilogue: bias + sigmoid, store f16 to heap position (col+1)&511
#pragma unroll
  for (int jn = 0; jn < 2; ++jn) {
    const int col = bn * 128 + wn * 32 + jn * 16 + (lane & 15);
    const float bb = (col < N_INNER) ? bias[col] : 0.f;
    const int hpos = (col + 1) & 511;
#pragma unroll
    for (int i = 0; i < 4; ++i) {
      const int rowb = bm * 128 + wm * 64 + i * 16 + ((lane >> 4) << 2);
#pragma unroll
      for (int r = 0; r < 4; ++r) {
        float v = acc[i][jn][r] + bb;
        v = 1.f / (1.f + __expf(-v));
        gates[(size_t)(rowb + r) * NPAD + hpos] = (_Float16)v;
      }
    }
  }
}

// ---------------- K2: tree expansion + GEMM2 (prob @ leaf_logits) ----------------
// 512 blocks x 32 rows, 512 threads. Phase1: 16 threads/row, 32 leaves each, heap-layout vector loads.
// Phase2: 7 waves x 1 n-frag, A from LDS (stride 520), B from LT global (L2-resident).
#define LPS 520

__global__ __launch_bounds__(512, 4) void k_tree(
    const _Float16* __restrict__ gates, const _Float16* __restrict__ LT,
    float* __restrict__ out) {
  __shared__ _Float16 lp[32 * LPS];

  const int t = threadIdx.x;
  const int rowl = t >> 4, sub = t & 15;
  const size_t grow = (size_t)blockIdx.x * 32 + rowl;
  const _Float16* g = gates + grow * NPAD;

  // vector-load gate slices (heap layout => aligned)
  const float f0 = (float)g[1];
  const float f1 = (float)g[2 + (sub >> 3)];
  const float f2 = (float)g[4 + (sub >> 2)];
  const float f3 = (float)g[8 + (sub >> 1)];
  const _Float16 g4 = g[16 + sub];
  const half2v g5 = *(const half2v*)(g + 32 + 2 * sub);
  const half4v g6 = *(const half4v*)(g + 64 + 4 * sub);
  const half8 g7 = *(const half8*)(g + 128 + 8 * sub);
  const half8 g8a = *(const half8*)(g + 256 + 16 * sub);
  const half8 g8b = *(const half8*)(g + 256 + 16 * sub + 8);

  float p = ((sub & 8) ? f0 : 1.f - f0) * ((sub & 4) ? f1 : 1.f - f1) *
            ((sub & 2) ? f2 : 1.f - f2) * ((sub & 1) ? f3 : 1.f - f3);

  float arr[32];
  // lvl4 (1 -> 2)
  {
    const float gg = (float)g4;
    arr[1] = p * gg; arr[0] = p - p * gg;
  }
  // lvl5 (2 -> 4)
#pragma unroll
  for (int i = 1; i >= 0; --i) {
    const float gg = (float)g5[i];
    const float pp = arr[i];
    arr[2 * i + 1] = pp * gg; arr[2 * i] = pp - pp * gg;
  }
  // lvl6 (4 -> 8)
#pragma unroll
  for (int i = 3; i >= 0; --i) {
    const float gg = (float)g6[i];
    const float pp = arr[i];
    arr[2 * i + 1] = pp * gg; arr[2 * i] = pp - pp * gg;
  }
  // lvl7 (8 -> 16)
#pragma unroll
  for (int i = 7; i >= 0; --i) {
    const float gg = (float)g7[i];
    const float pp = arr[i];
    arr[2 * i + 1] = pp * gg; arr[2 * i] = pp - pp * gg;
  }
  // lvl8 (16 -> 32)
#pragma unroll
  for (int i = 15; i >= 0; --i) {
    const float gg = (i < 8) ? (float)g8a[i] : (float)g8b[i - 8];
    const float pp = arr[i];
    arr[2 * i + 1] = pp * gg; arr[2 * i] = pp - pp * gg;
  }

  const int lb = sub * 32;
#pragma unroll
  for (int i = 0; i < 32; i += 8) {
    half8 h;
#pragma unroll
    for (int jj = 0; jj < 8; ++jj) h[jj] = (_Float16)arr[i + jj];
    *(half8*)&lp[rowl * LPS + lb + i] = h;
  }
  __syncthreads();

  // phase 2: waves 0..6 each own one 16-col n-frag; 2 m-frags of 16 rows
  const int lane = t & 63, w = t >> 6;
  if (w < 7) {
    f32x4 acc[2] = {};
#pragma unroll
    for (int k0 = 0; k0 < 512; k0 += 32) {
      const int n = w * 16 + (lane & 15);
      const half8 b8 = *(const half8*)&LT[(size_t)n * NPAD + k0 + (lane >> 4) * 8];
#pragma unroll
      for (int mf = 0; mf < 2; ++mf) {
        const half8 a = *(const half8*)&lp[(mf * 16 + (lane & 15)) * LPS + k0 + (lane >> 4) * 8];
        acc[mf] = __builtin_amdgcn_mfma_f32_16x16x32_f16(a, b8, acc[mf], 0, 0, 0);
      }
    }

    const int col = w * 16 + (lane & 15);
    if (col < NCLS) {
#pragma unroll
      for (int mf = 0; mf < 2; ++mf) {
        const int rowb = blockIdx.x * 32 + mf * 16 + ((lane >> 4) << 2);
#pragma unroll
        for (int r = 0; r < 4; ++r)
          out[(size_t)(rowb + r) * NCLS + col] = acc[mf][r];
      }
    }
  }
}

extern "C" void kernel_launch(void* const* d_in, const int* in_sizes, int n_in,
                              void* d_out, int out_size, void* d_ws, size_t ws_size,
                              hipStream_t stream) {
  const float* x = (const float*)d_in[0];
  const float* W = (const float*)d_in[1];
  const float* b = (const float*)d_in[2];
  const float* L = (const float*)d_in[3];
  float* out = (float*)d_out;

  char* ws = (char*)d_ws;
  _Float16* Wh = (_Float16*)ws;                                  // 512*1024*2 = 1 MB
  _Float16* LT = (_Float16*)(ws + (1u << 20));                   // 112*512*2 = 112 KB
  _Float16* gates = (_Float16*)(ws + (1u << 20) + 114688u);      // 16384*512*2 = 16 MB

  k_prep<<<2048, 256, 0, stream>>>(W, L, Wh, LT);
  k_gemm1<<<512, 512, 0, stream>>>(x, Wh, b, gates);
  k_tree<<<512, 512, 0, stream>>>(gates, LT, out);
}